// Round 6
// baseline (72.926 us; speedup 1.0000x reference)
//
#include <hip/hip_runtime.h>

#define NGRID 64
#define NEL (NGRID*NGRID*NGRID)   /* 262144 */
#define IDX(i,j,k) ((((i)*64 + (j)) * 64) + (k))

#define NSLAB   16                 /* slab = 4 consecutive i-planes = 16384 elements */
#define NTYPE   256
#define NBUCKET (NSLAB*NTYPE)      /* 4096 */
#define CAP     128                /* bucket capacity; count ~ Poisson(64), 8-sigma safe */

// ---- workspace layout (bytes) ----
// KUe32: 32 floats (128 B) per element, NATURAL element order (two full lines,
// written entirely by one thread; slab-pinned so lines merge in the XCD's L2).
#define WS_U4     0                                   // NEL float4 = 4 MB
#define WS_KUE    (WS_U4 + (size_t)NEL*16)            // NEL*128 B  = 33.5 MB
#define WS_SORTED (WS_KUE + (size_t)NEL*128)          // NBUCKET*CAP i32 = 2 MB
#define WS_CNT    (WS_SORTED + (size_t)NBUCKET*CAP*4) // NBUCKET i32 = 16 KB
#define WS_NEEDED (size_t)(WS_CNT + NBUCKET*4)

__device__ __forceinline__ int type_of(const float* __restrict__ rho, int i, int j, int k) {
    int i1 = (i + 1) & 63, j1 = (j + 1) & 63, k1 = (k + 1) & 63;
    // typeFilter[di][dj][dk] = 2^(di*4 + dj*2 + dk); OFFSETS order -> bits {0,4,2,6,1,5,3,7}
    int t = 0;
    t |= (rho[IDX(i,  j,  k )] > 0.5f ? 1 : 0) << 0;
    t |= (rho[IDX(i1, j,  k )] > 0.5f ? 1 : 0) << 4;
    t |= (rho[IDX(i,  j1, k )] > 0.5f ? 1 : 0) << 2;
    t |= (rho[IDX(i1, j1, k )] > 0.5f ? 1 : 0) << 6;
    t |= (rho[IDX(i,  j,  k1)] > 0.5f ? 1 : 0) << 1;
    t |= (rho[IDX(i1, j,  k1)] > 0.5f ? 1 : 0) << 5;
    t |= (rho[IDX(i,  j1, k1)] > 0.5f ? 1 : 0) << 3;
    t |= (rho[IDX(i1, j1, k1)] > 0.5f ? 1 : 0) << 7;
    return t;
}

// XCD-pinned slab mapping: first half of the grid covers slabs 0-7 (one per
// XCD via blockIdx%8 round-robin), second half slabs 8-15.
// K1: pack U->float4 + type + bucket-scatter via atomic rank. 1024 blocks x 256.
__global__ __launch_bounds__(256) void k1_pack_scatter(
    const float* __restrict__ U, const float* __restrict__ rho,
    float4* __restrict__ U4, int* __restrict__ cnt, int* __restrict__ sorted)
{
    int b = blockIdx.x;
    int slab  = (b & 7) + 8 * (b >> 9);
    int chunk = (b >> 3) & 63;
    int e = slab * 16384 + chunk * 256 + threadIdx.x;

    U4[e] = make_float4(U[3*e + 0], U[3*e + 1], U[3*e + 2], 0.0f);

    int k = e & 63, j = (e >> 6) & 63, i = (e >> 12) & 63;
    int t = type_of(rho, i, j, k);
    int bucket = slab * NTYPE + t;
    int pos = atomicAdd(&cnt[bucket], 1);
    if (pos < CAP) sorted[bucket * CAP + pos] = e;   // overflow impossible for this input
}

// K4: one block per (slab,type) bucket -> filter base is blockIdx-derived
// (pure SGPR / s_load path). Gather 8 float4 from slab-local U4, 24x24 matvec,
// write 8 float4 = 2 full lines at KUe32[e] (slab-local -> merges in L2).
__global__ __launch_bounds__(128) void k4_apply(
    const float4* __restrict__ U4, const float* __restrict__ filters,
    const int* __restrict__ sorted, const int* __restrict__ cnt,
    float4* __restrict__ KUe32)
{
    int b = blockIdx.x;                       // 4096 = NBUCKET
    int slab = (b & 7) + 8 * (b >> 11);
    int t    = (b >> 3) & 255;
    int bucket = slab * NTYPE + t;

    int n = cnt[bucket];
    if (n > CAP) n = CAP;
    if ((int)threadIdx.x >= n) return;

    const float* __restrict__ F = filters + t * 576;   // scalar base -> s_load

    int e = sorted[bucket * CAP + threadIdx.x];
    int k = e & 63, j = (e >> 6) & 63, i = (e >> 12) & 63;
    int i1 = (i + 1) & 63, j1 = (j + 1) & 63, k1 = (k + 1) & 63;

    int nodes[8];
    nodes[0] = IDX(i,  j,  k );
    nodes[1] = IDX(i1, j,  k );
    nodes[2] = IDX(i,  j1, k );
    nodes[3] = IDX(i1, j1, k );
    nodes[4] = IDX(i,  j,  k1);
    nodes[5] = IDX(i1, j,  k1);
    nodes[6] = IDX(i,  j1, k1);
    nodes[7] = IDX(i1, j1, k1);

    float Ue[24];
    #pragma unroll
    for (int m = 0; m < 8; ++m) {
        float4 u = U4[nodes[m]];
        Ue[3*m + 0] = u.x;
        Ue[3*m + 1] = u.y;
        Ue[3*m + 2] = u.z;
    }

    float o[24];
    #pragma unroll
    for (int r = 0; r < 24; ++r) {
        float a = 0.0f;
        #pragma unroll
        for (int q = 0; q < 24; ++q)
            a = fmaf(F[r * 24 + q], Ue[q], a);   // SGPR filter operand
        o[r] = a;
    }

    float4* __restrict__ dst = KUe32 + (size_t)e * 8;
    #pragma unroll
    for (int c = 0; c < 8; ++c)
        dst[c] = make_float4(o[3*c + 0], o[3*c + 1], o[3*c + 2], 0.0f);
}

// K5: per node n, sum corner-slot float4 of the 8 incident elements.
// Slab-pinned: reads are mostly the XCD's own KUe region (+1 halo plane).
__global__ __launch_bounds__(256) void k5_reduce(
    const float4* __restrict__ KUe32, float* __restrict__ out)
{
    int b = blockIdx.x;
    int slab  = (b & 7) + 8 * (b >> 9);
    int chunk = (b >> 3) & 63;
    int n = slab * 16384 + chunk * 256 + threadIdx.x;

    int k = n & 63, j = (n >> 6) & 63, i = (n >> 12) & 63;

    const int DI[8] = {0,1,0,1,0,1,0,1};
    const int DJ[8] = {0,0,1,1,0,0,1,1};
    const int DK[8] = {0,0,0,0,1,1,1,1};

    float a0 = 0.f, a1 = 0.f, a2 = 0.f;
    #pragma unroll
    for (int c = 0; c < 8; ++c) {
        int ei = (i - DI[c]) & 63;
        int ej = (j - DJ[c]) & 63;
        int ek = (k - DK[c]) & 63;
        float4 v = KUe32[(size_t)IDX(ei, ej, ek) * 8 + c];
        a0 += v.x; a1 += v.y; a2 += v.z;
    }
    out[n*3 + 0] = a0;
    out[n*3 + 1] = a1;
    out[n*3 + 2] = a2;
}

// Fallback (ws too small): round-1 atomic scatter kernel.
__global__ __launch_bounds__(256) void fe_apply_atomic(
    const float* __restrict__ U, const float* __restrict__ rho,
    const float* __restrict__ filters, float* __restrict__ out)
{
    int e = blockIdx.x * blockDim.x + threadIdx.x;
    int k = e & 63, j = (e >> 6) & 63, i = (e >> 12) & 63;
    int i1 = (i + 1) & 63, j1 = (j + 1) & 63, k1 = (k + 1) & 63;
    int nodes[8];
    nodes[0]=IDX(i,j,k);   nodes[1]=IDX(i1,j,k);   nodes[2]=IDX(i,j1,k);   nodes[3]=IDX(i1,j1,k);
    nodes[4]=IDX(i,j,k1);  nodes[5]=IDX(i1,j,k1);  nodes[6]=IDX(i,j1,k1);  nodes[7]=IDX(i1,j1,k1);
    int t = type_of(rho, i, j, k);
    float Ue[24];
    #pragma unroll
    for (int m = 0; m < 8; ++m) {
        int bb = nodes[m] * 3;
        Ue[3*m+0]=U[bb+0]; Ue[3*m+1]=U[bb+1]; Ue[3*m+2]=U[bb+2];
    }
    const float4* Kr = (const float4*)(filters + t * 576);
    #pragma unroll
    for (int r = 0; r < 24; ++r) {
        float a = 0.f;
        #pragma unroll
        for (int q = 0; q < 6; ++q) {
            float4 f = Kr[r*6+q];
            a = fmaf(f.x,Ue[4*q+0],a); a = fmaf(f.y,Ue[4*q+1],a);
            a = fmaf(f.z,Ue[4*q+2],a); a = fmaf(f.w,Ue[4*q+3],a);
        }
        atomicAdd(&out[nodes[r/3]*3 + (r%3)], a);
    }
}

extern "C" void kernel_launch(void* const* d_in, const int* in_sizes, int n_in,
                              void* d_out, int out_size, void* d_ws, size_t ws_size,
                              hipStream_t stream) {
    const float* U       = (const float*)d_in[0];
    const float* rho     = (const float*)d_in[1];
    const float* filters = (const float*)d_in[3];
    float* out = (float*)d_out;

    if (ws_size < WS_NEEDED) {
        hipMemsetAsync(out, 0, (size_t)out_size * sizeof(float), stream);
        fe_apply_atomic<<<dim3(NEL/256), dim3(256), 0, stream>>>(U, rho, filters, out);
        return;
    }

    char* ws = (char*)d_ws;
    float4* U4     = (float4*)(ws + WS_U4);
    float4* KUe32  = (float4*)(ws + WS_KUE);
    int*    sorted = (int*)(ws + WS_SORTED);
    int*    cnt    = (int*)(ws + WS_CNT);

    hipMemsetAsync(cnt, 0, NBUCKET * sizeof(int), stream);
    k1_pack_scatter<<<dim3(1024),    dim3(256), 0, stream>>>(U, rho, U4, cnt, sorted);
    k4_apply       <<<dim3(NBUCKET), dim3(128), 0, stream>>>(U4, filters, sorted, cnt, KUe32);
    k5_reduce      <<<dim3(1024),    dim3(256), 0, stream>>>(KUe32, out);
}

// Round 7
// 72.235 us; speedup vs baseline: 1.0096x; 1.0096x over previous
//
#include <hip/hip_runtime.h>

#define NGRID 64
#define NEL (NGRID*NGRID*NGRID)   /* 262144 */
#define IDX(i,j,k) ((((i)*64 + (j)) * 64) + (k))

#define NSLAB   16                 /* slab = 4 consecutive i-planes = 16384 elements */
#define NTYPE   256
#define NBUCKET (NSLAB*NTYPE)      /* 4096 */
#define CAP     128                /* bucket capacity; count ~ Poisson(64), 8-sigma safe */

// ---- workspace layout (bytes) ----
// KUe32: 32 floats (128 B) per element, NATURAL element order (two full lines,
// written entirely by one thread; slab-pinned so lines merge in the XCD's L2).
#define WS_U4     0                                   // NEL float4 = 4 MB
#define WS_KUE    (WS_U4 + (size_t)NEL*16)            // NEL*128 B  = 33.5 MB
#define WS_SORTED (WS_KUE + (size_t)NEL*128)          // NBUCKET*CAP i32 = 2 MB
#define WS_CNT    (WS_SORTED + (size_t)NBUCKET*CAP*4) // NBUCKET i32 = 16 KB
#define WS_NEEDED (size_t)(WS_CNT + NBUCKET*4)

__device__ __forceinline__ int type_of(const float* __restrict__ rho, int i, int j, int k) {
    int i1 = (i + 1) & 63, j1 = (j + 1) & 63, k1 = (k + 1) & 63;
    // typeFilter[di][dj][dk] = 2^(di*4 + dj*2 + dk); OFFSETS order -> bits {0,4,2,6,1,5,3,7}
    int t = 0;
    t |= (rho[IDX(i,  j,  k )] > 0.5f ? 1 : 0) << 0;
    t |= (rho[IDX(i1, j,  k )] > 0.5f ? 1 : 0) << 4;
    t |= (rho[IDX(i,  j1, k )] > 0.5f ? 1 : 0) << 2;
    t |= (rho[IDX(i1, j1, k )] > 0.5f ? 1 : 0) << 6;
    t |= (rho[IDX(i,  j,  k1)] > 0.5f ? 1 : 0) << 1;
    t |= (rho[IDX(i1, j,  k1)] > 0.5f ? 1 : 0) << 5;
    t |= (rho[IDX(i,  j1, k1)] > 0.5f ? 1 : 0) << 3;
    t |= (rho[IDX(i1, j1, k1)] > 0.5f ? 1 : 0) << 7;
    return t;
}

// K0: zero the 4096 bucket counters (replaces hipMemsetAsync — a 16 KB memset
// node inside the captured graph cost ~48 us/replay as fillBufferAligned).
__global__ __launch_bounds__(1024) void k0_zero(int* __restrict__ cnt)
{
    int tid = threadIdx.x;
    #pragma unroll
    for (int q = 0; q < NBUCKET / 1024; ++q)
        cnt[q * 1024 + tid] = 0;
}

// XCD-pinned slab mapping: first half of the grid covers slabs 0-7 (one per
// XCD via blockIdx%8 round-robin), second half slabs 8-15.
// K1: pack U->float4 + type + bucket-scatter via atomic rank. 1024 blocks x 256.
__global__ __launch_bounds__(256) void k1_pack_scatter(
    const float* __restrict__ U, const float* __restrict__ rho,
    float4* __restrict__ U4, int* __restrict__ cnt, int* __restrict__ sorted)
{
    int b = blockIdx.x;
    int slab  = (b & 7) + 8 * (b >> 9);
    int chunk = (b >> 3) & 63;
    int e = slab * 16384 + chunk * 256 + threadIdx.x;

    U4[e] = make_float4(U[3*e + 0], U[3*e + 1], U[3*e + 2], 0.0f);

    int k = e & 63, j = (e >> 6) & 63, i = (e >> 12) & 63;
    int t = type_of(rho, i, j, k);
    int bucket = slab * NTYPE + t;
    int pos = atomicAdd(&cnt[bucket], 1);
    if (pos < CAP) sorted[bucket * CAP + pos] = e;   // overflow impossible for this input
}

// K4: one block per (slab,type) bucket -> filter base is blockIdx-derived
// (pure SGPR / s_load path). Gather 8 float4 from slab-local U4, 24x24 matvec,
// write 8 float4 = 2 full lines at KUe32[e] (slab-local -> merges in L2).
__global__ __launch_bounds__(128) void k4_apply(
    const float4* __restrict__ U4, const float* __restrict__ filters,
    const int* __restrict__ sorted, const int* __restrict__ cnt,
    float4* __restrict__ KUe32)
{
    int b = blockIdx.x;                       // 4096 = NBUCKET
    int slab = (b & 7) + 8 * (b >> 11);
    int t    = (b >> 3) & 255;
    int bucket = slab * NTYPE + t;

    int n = cnt[bucket];
    if (n > CAP) n = CAP;
    if ((int)threadIdx.x >= n) return;

    const float* __restrict__ F = filters + t * 576;   // scalar base -> s_load

    int e = sorted[bucket * CAP + threadIdx.x];
    int k = e & 63, j = (e >> 6) & 63, i = (e >> 12) & 63;
    int i1 = (i + 1) & 63, j1 = (j + 1) & 63, k1 = (k + 1) & 63;

    int nodes[8];
    nodes[0] = IDX(i,  j,  k );
    nodes[1] = IDX(i1, j,  k );
    nodes[2] = IDX(i,  j1, k );
    nodes[3] = IDX(i1, j1, k );
    nodes[4] = IDX(i,  j,  k1);
    nodes[5] = IDX(i1, j,  k1);
    nodes[6] = IDX(i,  j1, k1);
    nodes[7] = IDX(i1, j1, k1);

    float Ue[24];
    #pragma unroll
    for (int m = 0; m < 8; ++m) {
        float4 u = U4[nodes[m]];
        Ue[3*m + 0] = u.x;
        Ue[3*m + 1] = u.y;
        Ue[3*m + 2] = u.z;
    }

    float o[24];
    #pragma unroll
    for (int r = 0; r < 24; ++r) {
        float a = 0.0f;
        #pragma unroll
        for (int q = 0; q < 24; ++q)
            a = fmaf(F[r * 24 + q], Ue[q], a);   // SGPR filter operand
        o[r] = a;
    }

    float4* __restrict__ dst = KUe32 + (size_t)e * 8;
    #pragma unroll
    for (int c = 0; c < 8; ++c)
        dst[c] = make_float4(o[3*c + 0], o[3*c + 1], o[3*c + 2], 0.0f);
}

// K5: per node n, sum corner-slot float4 of the 8 incident elements.
// Slab-pinned: reads are mostly the XCD's own KUe region (+1 halo plane).
__global__ __launch_bounds__(256) void k5_reduce(
    const float4* __restrict__ KUe32, float* __restrict__ out)
{
    int b = blockIdx.x;
    int slab  = (b & 7) + 8 * (b >> 9);
    int chunk = (b >> 3) & 63;
    int n = slab * 16384 + chunk * 256 + threadIdx.x;

    int k = n & 63, j = (n >> 6) & 63, i = (n >> 12) & 63;

    const int DI[8] = {0,1,0,1,0,1,0,1};
    const int DJ[8] = {0,0,1,1,0,0,1,1};
    const int DK[8] = {0,0,0,0,1,1,1,1};

    float a0 = 0.f, a1 = 0.f, a2 = 0.f;
    #pragma unroll
    for (int c = 0; c < 8; ++c) {
        int ei = (i - DI[c]) & 63;
        int ej = (j - DJ[c]) & 63;
        int ek = (k - DK[c]) & 63;
        float4 v = KUe32[(size_t)IDX(ei, ej, ek) * 8 + c];
        a0 += v.x; a1 += v.y; a2 += v.z;
    }
    out[n*3 + 0] = a0;
    out[n*3 + 1] = a1;
    out[n*3 + 2] = a2;
}

// Fallback (ws too small): round-1 atomic scatter kernel.
__global__ __launch_bounds__(256) void fe_apply_atomic(
    const float* __restrict__ U, const float* __restrict__ rho,
    const float* __restrict__ filters, float* __restrict__ out)
{
    int e = blockIdx.x * blockDim.x + threadIdx.x;
    int k = e & 63, j = (e >> 6) & 63, i = (e >> 12) & 63;
    int i1 = (i + 1) & 63, j1 = (j + 1) & 63, k1 = (k + 1) & 63;
    int nodes[8];
    nodes[0]=IDX(i,j,k);   nodes[1]=IDX(i1,j,k);   nodes[2]=IDX(i,j1,k);   nodes[3]=IDX(i1,j1,k);
    nodes[4]=IDX(i,j,k1);  nodes[5]=IDX(i1,j,k1);  nodes[6]=IDX(i,j1,k1);  nodes[7]=IDX(i1,j1,k1);
    int t = type_of(rho, i, j, k);
    float Ue[24];
    #pragma unroll
    for (int m = 0; m < 8; ++m) {
        int bb = nodes[m] * 3;
        Ue[3*m+0]=U[bb+0]; Ue[3*m+1]=U[bb+1]; Ue[3*m+2]=U[bb+2];
    }
    const float4* Kr = (const float4*)(filters + t * 576);
    #pragma unroll
    for (int r = 0; r < 24; ++r) {
        float a = 0.f;
        #pragma unroll
        for (int q = 0; q < 6; ++q) {
            float4 f = Kr[r*6+q];
            a = fmaf(f.x,Ue[4*q+0],a); a = fmaf(f.y,Ue[4*q+1],a);
            a = fmaf(f.z,Ue[4*q+2],a); a = fmaf(f.w,Ue[4*q+3],a);
        }
        atomicAdd(&out[nodes[r/3]*3 + (r%3)], a);
    }
}

extern "C" void kernel_launch(void* const* d_in, const int* in_sizes, int n_in,
                              void* d_out, int out_size, void* d_ws, size_t ws_size,
                              hipStream_t stream) {
    const float* U       = (const float*)d_in[0];
    const float* rho     = (const float*)d_in[1];
    const float* filters = (const float*)d_in[3];
    float* out = (float*)d_out;

    if (ws_size < WS_NEEDED) {
        hipMemsetAsync(out, 0, (size_t)out_size * sizeof(float), stream);
        fe_apply_atomic<<<dim3(NEL/256), dim3(256), 0, stream>>>(U, rho, filters, out);
        return;
    }

    char* ws = (char*)d_ws;
    float4* U4     = (float4*)(ws + WS_U4);
    float4* KUe32  = (float4*)(ws + WS_KUE);
    int*    sorted = (int*)(ws + WS_SORTED);
    int*    cnt    = (int*)(ws + WS_CNT);

    k0_zero        <<<dim3(1),       dim3(1024), 0, stream>>>(cnt);
    k1_pack_scatter<<<dim3(1024),    dim3(256),  0, stream>>>(U, rho, U4, cnt, sorted);
    k4_apply       <<<dim3(NBUCKET), dim3(128),  0, stream>>>(U4, filters, sorted, cnt, KUe32);
    k5_reduce      <<<dim3(1024),    dim3(256),  0, stream>>>(KUe32, out);
}

// Round 8
// 54.009 us; speedup vs baseline: 1.3503x; 1.3375x over previous
//
#include <hip/hip_runtime.h>

#define NGRID 64
#define NEL (NGRID*NGRID*NGRID)   /* 262144 */
#define IDX(i,j,k) ((((i)*64 + (j)) * 64) + (k))

#define NSLAB    16                /* slab = 4 consecutive i-planes = 16384 elements */
#define SLAB_EL  16384
#define NTYPE    256
#define SLAB_PAD 32768             /* per-slab sorted region: 16384 + 256*64 worst-case padding */
#define PADTOT   (NSLAB*SLAB_PAD)  /* 524288 */

// ---- workspace layout (bytes) ----
#define WS_U4     0                                   // NEL float4 = 4 MB
#define WS_KUE    (WS_U4 + (size_t)NEL*16)            // NEL*128 B  = 33.5 MB
#define WS_SORTED (WS_KUE + (size_t)NEL*128)          // PADTOT i32 = 2 MB
#define WS_TYPES  (WS_SORTED + (size_t)PADTOT*4)      // NEL u8 = 256 KB
#define WS_BHIST  (WS_TYPES + NEL)                    // 4096*16 i32 = 256 KB ([slab][type][inner16])
#define WS_NEEDED (size_t)(WS_BHIST + 4096*16*4)

__device__ __forceinline__ int type_of(const float* __restrict__ rho, int i, int j, int k) {
    int i1 = (i + 1) & 63, j1 = (j + 1) & 63, k1 = (k + 1) & 63;
    // typeFilter[di][dj][dk] = 2^(di*4 + dj*2 + dk); OFFSETS order -> bits {0,4,2,6,1,5,3,7}
    int t = 0;
    t |= (rho[IDX(i,  j,  k )] > 0.5f ? 1 : 0) << 0;
    t |= (rho[IDX(i1, j,  k )] > 0.5f ? 1 : 0) << 4;
    t |= (rho[IDX(i,  j1, k )] > 0.5f ? 1 : 0) << 2;
    t |= (rho[IDX(i1, j1, k )] > 0.5f ? 1 : 0) << 6;
    t |= (rho[IDX(i,  j,  k1)] > 0.5f ? 1 : 0) << 1;
    t |= (rho[IDX(i1, j,  k1)] > 0.5f ? 1 : 0) << 5;
    t |= (rho[IDX(i,  j1, k1)] > 0.5f ? 1 : 0) << 3;
    t |= (rho[IDX(i1, j1, k1)] > 0.5f ? 1 : 0) << 7;
    return t;
}

// K1: 256 blocks x 1024 thr. slab = b&15 (XCD-pinned: slab%8 == b%8),
// inner = b>>4. Pack U->float4, types, per-(slab,type,inner) LDS hist
// (NO global atomics), init this block's sorted subregion to -1.
__global__ __launch_bounds__(1024) void k1_hist(
    const float* __restrict__ U, const float* __restrict__ rho,
    float4* __restrict__ U4, unsigned char* __restrict__ types,
    int* __restrict__ bhist, int* __restrict__ sorted)
{
    __shared__ int lh[NTYPE];
    int tid = threadIdx.x;
    int b = blockIdx.x;
    int slab = b & 15, inner = b >> 4;
    if (tid < NTYPE) lh[tid] = 0;

    // init our 1/16th of the slab's padded sorted region
    int* sreg = sorted + slab * SLAB_PAD + inner * (SLAB_PAD / 16);
    sreg[tid] = -1;
    sreg[1024 + tid] = -1;
    __syncthreads();

    int e = slab * SLAB_EL + inner * 1024 + tid;
    U4[e] = make_float4(U[3*e + 0], U[3*e + 1], U[3*e + 2], 0.0f);
    int k = e & 63, j = (e >> 6) & 63, i = (e >> 12) & 63;
    int t = type_of(rho, i, j, k);
    types[e] = (unsigned char)t;
    atomicAdd(&lh[t], 1);                 // LDS-only atomic
    __syncthreads();
    if (tid < NTYPE) bhist[(slab * NTYPE + tid) * 16 + inner] = lh[tid];
}

// K2: 16 blocks (one per slab) x 256 thr (one per type). Sum the 16 inner
// counts, pad bucket to 64, exclusive-scan padded sizes across types (LDS),
// rewrite bhist as absolute start offsets per (slab,type,inner).
__global__ __launch_bounds__(256) void k2_scan(int* __restrict__ bhist)
{
    int slab = blockIdx.x, t = threadIdx.x;
    int base = (slab * NTYPE + t) * 16;
    int c[16], sum = 0;
    #pragma unroll
    for (int in = 0; in < 16; ++in) { c[in] = bhist[base + in]; sum += c[in]; }
    int padded = (sum + 63) & ~63;

    __shared__ int s[256];
    s[t] = padded;
    __syncthreads();
    #pragma unroll
    for (int off = 1; off < 256; off <<= 1) {
        int tmp = (t >= off) ? s[t - off] : 0;
        __syncthreads();
        s[t] += tmp;
        __syncthreads();
    }
    int run = slab * SLAB_PAD + (s[t] - padded);   // exclusive scan start
    #pragma unroll
    for (int in = 0; in < 16; ++in) { bhist[base + in] = run; run += c[in]; }
}

// K3: same geometry as K1. LDS rank within (block,type), position from bhist
// offsets. No global atomics. Write (t<<18)|e.
__global__ __launch_bounds__(1024) void k3_scatter(
    const unsigned char* __restrict__ types, const int* __restrict__ bhist,
    int* __restrict__ sorted)
{
    __shared__ int lh[NTYPE];
    int tid = threadIdx.x;
    int b = blockIdx.x;
    int slab = b & 15, inner = b >> 4;
    if (tid < NTYPE) lh[tid] = 0;
    __syncthreads();
    int e = slab * SLAB_EL + inner * 1024 + tid;
    int t = types[e];
    int rank = atomicAdd(&lh[t], 1);      // LDS-only atomic
    int pos = bhist[(slab * NTYPE + t) * 16 + inner] + rank;
    sorted[pos] = (t << 18) | e;
}

// K4: 2048 blocks x 256 thr over the padded sorted stream. Buckets are
// 64-padded -> every wave is type-pure -> readfirstlane filter base (s_load).
// slab = (b&7) + 8*(hi>>7) keeps each slab on its own XCD; U4 reads and the
// 2-full-line KUe writes stay in that XCD's L2.
__global__ __launch_bounds__(256) void k4_apply(
    const float4* __restrict__ U4, const float* __restrict__ filters,
    const int* __restrict__ sorted, float4* __restrict__ KUe32)
{
    int b = blockIdx.x;
    int hi = b >> 3;
    int slab = (b & 7) + 8 * (hi >> 7);
    int inner = hi & 127;
    int p = slab * SLAB_PAD + inner * 256 + threadIdx.x;

    int entry = sorted[p];
    int tw = __builtin_amdgcn_readfirstlane(entry);
    int t = (tw >> 18) & 255;                    // all-hole waves: harmless dummy
    const float* __restrict__ F = filters + t * 576;   // SGPR base -> s_load

    if (entry >= 0) {
        int e = entry & 0x3FFFF;
        int k = e & 63, j = (e >> 6) & 63, i = (e >> 12) & 63;
        int i1 = (i + 1) & 63, j1 = (j + 1) & 63, k1 = (k + 1) & 63;

        int nodes[8];
        nodes[0] = IDX(i,  j,  k );
        nodes[1] = IDX(i1, j,  k );
        nodes[2] = IDX(i,  j1, k );
        nodes[3] = IDX(i1, j1, k );
        nodes[4] = IDX(i,  j,  k1);
        nodes[5] = IDX(i1, j,  k1);
        nodes[6] = IDX(i,  j1, k1);
        nodes[7] = IDX(i1, j1, k1);

        float Ue[24];
        #pragma unroll
        for (int m = 0; m < 8; ++m) {
            float4 u = U4[nodes[m]];
            Ue[3*m + 0] = u.x;
            Ue[3*m + 1] = u.y;
            Ue[3*m + 2] = u.z;
        }

        float o[24];
        #pragma unroll
        for (int r = 0; r < 24; ++r) {
            float a = 0.0f;
            #pragma unroll
            for (int q = 0; q < 24; ++q)
                a = fmaf(F[r * 24 + q], Ue[q], a);   // SGPR filter operand
            o[r] = a;
        }

        float4* __restrict__ dst = KUe32 + (size_t)e * 8;
        #pragma unroll
        for (int c = 0; c < 8; ++c)
            dst[c] = make_float4(o[3*c + 0], o[3*c + 1], o[3*c + 2], 0.0f);
    }
}

// K5: per node n, sum corner-slot float4 of the 8 incident elements.
// Slab-pinned: reads mostly the XCD's own KUe region (+1 halo plane).
__global__ __launch_bounds__(256) void k5_reduce(
    const float4* __restrict__ KUe32, float* __restrict__ out)
{
    int b = blockIdx.x;
    int slab  = (b & 7) + 8 * (b >> 9);
    int chunk = (b >> 3) & 63;
    int n = slab * SLAB_EL + chunk * 256 + threadIdx.x;

    int k = n & 63, j = (n >> 6) & 63, i = (n >> 12) & 63;

    const int DI[8] = {0,1,0,1,0,1,0,1};
    const int DJ[8] = {0,0,1,1,0,0,1,1};
    const int DK[8] = {0,0,0,0,1,1,1,1};

    float a0 = 0.f, a1 = 0.f, a2 = 0.f;
    #pragma unroll
    for (int c = 0; c < 8; ++c) {
        int ei = (i - DI[c]) & 63;
        int ej = (j - DJ[c]) & 63;
        int ek = (k - DK[c]) & 63;
        float4 v = KUe32[(size_t)IDX(ei, ej, ek) * 8 + c];
        a0 += v.x; a1 += v.y; a2 += v.z;
    }
    out[n*3 + 0] = a0;
    out[n*3 + 1] = a1;
    out[n*3 + 2] = a2;
}

// Fallback (ws too small): round-1 atomic scatter kernel.
__global__ __launch_bounds__(256) void fe_apply_atomic(
    const float* __restrict__ U, const float* __restrict__ rho,
    const float* __restrict__ filters, float* __restrict__ out)
{
    int e = blockIdx.x * blockDim.x + threadIdx.x;
    int k = e & 63, j = (e >> 6) & 63, i = (e >> 12) & 63;
    int i1 = (i + 1) & 63, j1 = (j + 1) & 63, k1 = (k + 1) & 63;
    int nodes[8];
    nodes[0]=IDX(i,j,k);   nodes[1]=IDX(i1,j,k);   nodes[2]=IDX(i,j1,k);   nodes[3]=IDX(i1,j1,k);
    nodes[4]=IDX(i,j,k1);  nodes[5]=IDX(i1,j,k1);  nodes[6]=IDX(i,j1,k1);  nodes[7]=IDX(i1,j1,k1);
    int t = type_of(rho, i, j, k);
    float Ue[24];
    #pragma unroll
    for (int m = 0; m < 8; ++m) {
        int bb = nodes[m] * 3;
        Ue[3*m+0]=U[bb+0]; Ue[3*m+1]=U[bb+1]; Ue[3*m+2]=U[bb+2];
    }
    const float4* Kr = (const float4*)(filters + t * 576);
    #pragma unroll
    for (int r = 0; r < 24; ++r) {
        float a = 0.f;
        #pragma unroll
        for (int q = 0; q < 6; ++q) {
            float4 f = Kr[r*6+q];
            a = fmaf(f.x,Ue[4*q+0],a); a = fmaf(f.y,Ue[4*q+1],a);
            a = fmaf(f.z,Ue[4*q+2],a); a = fmaf(f.w,Ue[4*q+3],a);
        }
        atomicAdd(&out[nodes[r/3]*3 + (r%3)], a);
    }
}

extern "C" void kernel_launch(void* const* d_in, const int* in_sizes, int n_in,
                              void* d_out, int out_size, void* d_ws, size_t ws_size,
                              hipStream_t stream) {
    const float* U       = (const float*)d_in[0];
    const float* rho     = (const float*)d_in[1];
    const float* filters = (const float*)d_in[3];
    float* out = (float*)d_out;

    if (ws_size < WS_NEEDED) {
        hipMemsetAsync(out, 0, (size_t)out_size * sizeof(float), stream);
        fe_apply_atomic<<<dim3(NEL/256), dim3(256), 0, stream>>>(U, rho, filters, out);
        return;
    }

    char* ws = (char*)d_ws;
    float4*        U4     = (float4*)(ws + WS_U4);
    float4*        KUe32  = (float4*)(ws + WS_KUE);
    int*           sorted = (int*)(ws + WS_SORTED);
    unsigned char* types  = (unsigned char*)(ws + WS_TYPES);
    int*           bhist  = (int*)(ws + WS_BHIST);

    k1_hist   <<<dim3(256),  dim3(1024), 0, stream>>>(U, rho, U4, types, bhist, sorted);
    k2_scan   <<<dim3(16),   dim3(256),  0, stream>>>(bhist);
    k3_scatter<<<dim3(256),  dim3(1024), 0, stream>>>(types, bhist, sorted);
    k4_apply  <<<dim3(2048), dim3(256),  0, stream>>>(U4, filters, sorted, KUe32);
    k5_reduce <<<dim3(1024), dim3(256),  0, stream>>>(KUe32, out);
}

// Round 9
// 40.055 us; speedup vs baseline: 1.8206x; 1.3484x over previous
//
#include <hip/hip_runtime.h>
#include <hip/hip_fp16.h>

#define NGRID 64
#define NEL (NGRID*NGRID*NGRID)   /* 262144 */
#define IDX(i,j,k) ((((i)*64 + (j)) * 64) + (k))

#define NSLAB    16                /* slab = 4 consecutive i-planes = 16384 elements */
#define SLAB_EL  16384
#define NTYPE    256
#define SLAB_PAD 32768             /* per-slab sorted region (worst-case 64-padding) */
#define PADTOT   (NSLAB*SLAB_PAD)  /* 524288 */
#define NSLOT    (PADTOT/64)       /* 8192 slot-table entries */
#define SLAB_SLOTS (SLAB_PAD/64)   /* 512 */

// ---- workspace layout (bytes) ----
// KUe16: 64 B per element (8 corners x half4{x,y,z,pad}), NATURAL element
// order. One full cache line per element written by one thread -> no RMW.
#define WS_U4     0                                   // NEL float4 = 4 MB
#define WS_KUE    (WS_U4 + (size_t)NEL*16)            // NEL*64 B  = 16 MB
#define WS_SORTED (WS_KUE + (size_t)NEL*64)           // PADTOT i32 = 2 MB
#define WS_TYPES  (WS_SORTED + (size_t)PADTOT*4)      // NEL u8 = 256 KB
#define WS_BHIST  (WS_TYPES + NEL)                    // 4096*16 i32 ([slab][type][inner16])
#define WS_SLOT   (WS_BHIST + 4096*16*4)              // NSLOT i32 = 32 KB
#define WS_NEEDED (size_t)(WS_SLOT + NSLOT*4)

__device__ __forceinline__ int type_of(const float* __restrict__ rho, int i, int j, int k) {
    int i1 = (i + 1) & 63, j1 = (j + 1) & 63, k1 = (k + 1) & 63;
    // typeFilter[di][dj][dk] = 2^(di*4 + dj*2 + dk); OFFSETS order -> bits {0,4,2,6,1,5,3,7}
    int t = 0;
    t |= (rho[IDX(i,  j,  k )] > 0.5f ? 1 : 0) << 0;
    t |= (rho[IDX(i1, j,  k )] > 0.5f ? 1 : 0) << 4;
    t |= (rho[IDX(i,  j1, k )] > 0.5f ? 1 : 0) << 2;
    t |= (rho[IDX(i1, j1, k )] > 0.5f ? 1 : 0) << 6;
    t |= (rho[IDX(i,  j,  k1)] > 0.5f ? 1 : 0) << 1;
    t |= (rho[IDX(i1, j,  k1)] > 0.5f ? 1 : 0) << 5;
    t |= (rho[IDX(i,  j1, k1)] > 0.5f ? 1 : 0) << 3;
    t |= (rho[IDX(i1, j1, k1)] > 0.5f ? 1 : 0) << 7;
    return t;
}

// K1: 256 blocks x 1024 thr; slab = b&15, inner = b>>4.
// Pack U->float4, types, per-(slab,type,inner) LDS histogram. No global atomics.
__global__ __launch_bounds__(1024) void k1_hist(
    const float* __restrict__ U, const float* __restrict__ rho,
    float4* __restrict__ U4, unsigned char* __restrict__ types,
    int* __restrict__ bhist)
{
    __shared__ int lh[NTYPE];
    int tid = threadIdx.x;
    int b = blockIdx.x;
    int slab = b & 15, inner = b >> 4;
    if (tid < NTYPE) lh[tid] = 0;
    __syncthreads();

    int e = slab * SLAB_EL + inner * 1024 + tid;
    U4[e] = make_float4(U[3*e + 0], U[3*e + 1], U[3*e + 2], 0.0f);
    int k = e & 63, j = (e >> 6) & 63, i = (e >> 12) & 63;
    int t = type_of(rho, i, j, k);
    types[e] = (unsigned char)t;
    atomicAdd(&lh[t], 1);                 // LDS-only atomic
    __syncthreads();
    if (tid < NTYPE) bhist[(slab * NTYPE + tid) * 16 + inner] = lh[tid];
}

// K2: 16 blocks (slab) x 256 thr (type). Sum inner counts, 64-pad, scan across
// types; rewrite bhist as absolute start offsets; emit per-64-slot table
// entries (count<<8)|type; zero the slab's unused tail slots.
__global__ __launch_bounds__(256) void k2_scan(
    int* __restrict__ bhist, int* __restrict__ slotinfo)
{
    int slab = blockIdx.x, t = threadIdx.x;
    int base = (slab * NTYPE + t) * 16;
    int c[16], sum = 0;
    #pragma unroll
    for (int in = 0; in < 16; ++in) { c[in] = bhist[base + in]; sum += c[in]; }
    int padded = (sum + 63) & ~63;

    __shared__ int s[256];
    __shared__ int used;
    s[t] = padded;
    __syncthreads();
    #pragma unroll
    for (int off = 1; off < 256; off <<= 1) {
        int tmp = (t >= off) ? s[t - off] : 0;
        __syncthreads();
        s[t] += tmp;
        __syncthreads();
    }
    int excl = s[t] - padded;                      // exclusive scan, mult of 64
    int run = slab * SLAB_PAD + excl;
    #pragma unroll
    for (int in = 0; in < 16; ++in) { bhist[base + in] = run; run += c[in]; }

    // slot table for this bucket
    int slot0 = slab * SLAB_SLOTS + (excl >> 6);
    int nslots = padded >> 6;
    for (int q = 0; q < nslots; ++q) {
        int cq = sum - (q << 6);
        cq = cq > 64 ? 64 : cq;                    // >=1 here
        slotinfo[slot0 + q] = (cq << 8) | t;
    }
    if (t == 255) used = s[255] >> 6;
    __syncthreads();
    for (int q = used + t; q < SLAB_SLOTS; q += 256)
        slotinfo[slab * SLAB_SLOTS + q] = 0;       // all-hole tail slots
}

// K3: same geometry as K1. LDS rank within (block,type); write element id.
__global__ __launch_bounds__(1024) void k3_scatter(
    const unsigned char* __restrict__ types, const int* __restrict__ bhist,
    int* __restrict__ sorted)
{
    __shared__ int lh[NTYPE];
    int tid = threadIdx.x;
    int b = blockIdx.x;
    int slab = b & 15, inner = b >> 4;
    if (tid < NTYPE) lh[tid] = 0;
    __syncthreads();
    int e = slab * SLAB_EL + inner * 1024 + tid;
    int t = types[e];
    int rank = atomicAdd(&lh[t], 1);      // LDS-only atomic
    int pos = bhist[(slab * NTYPE + t) * 16 + inner] + rank;
    sorted[pos] = e;
}

// K4: 2048 blocks x 256 thr over the padded sorted stream. Each wave reads its
// slot entry (wave-uniform -> s_load): type + active count, both scalar.
// Gather 8 float4 from slab-local U4, 24x24 matvec (SGPR filter), write one
// full 64 B line of fp16 KUe.
__global__ __launch_bounds__(256) void k4_apply(
    const float4* __restrict__ U4, const float* __restrict__ filters,
    const int* __restrict__ sorted, const int* __restrict__ slotinfo,
    float4* __restrict__ KUe16)
{
    int b = blockIdx.x;
    int hi = b >> 3;
    int slab = (b & 7) + 8 * (hi >> 7);
    int inner = hi & 127;
    int p = slab * SLAB_PAD + inner * 256 + threadIdx.x;

    int slot = __builtin_amdgcn_readfirstlane(p >> 6);   // wave-uniform
    int packed = slotinfo[slot];                         // scalar load
    int t   = packed & 255;
    int cnt = packed >> 8;
    const float* __restrict__ F = filters + t * 576;     // SGPR base -> s_load

    if ((int)(threadIdx.x & 63) < cnt) {
        int e = sorted[p];
        int k = e & 63, j = (e >> 6) & 63, i = (e >> 12) & 63;
        int i1 = (i + 1) & 63, j1 = (j + 1) & 63, k1 = (k + 1) & 63;

        int nodes[8];
        nodes[0] = IDX(i,  j,  k );
        nodes[1] = IDX(i1, j,  k );
        nodes[2] = IDX(i,  j1, k );
        nodes[3] = IDX(i1, j1, k );
        nodes[4] = IDX(i,  j,  k1);
        nodes[5] = IDX(i1, j,  k1);
        nodes[6] = IDX(i,  j1, k1);
        nodes[7] = IDX(i1, j1, k1);

        float Ue[24];
        #pragma unroll
        for (int m = 0; m < 8; ++m) {
            float4 u = U4[nodes[m]];
            Ue[3*m + 0] = u.x;
            Ue[3*m + 1] = u.y;
            Ue[3*m + 2] = u.z;
        }

        float o[24];
        #pragma unroll
        for (int r = 0; r < 24; ++r) {
            float a = 0.0f;
            #pragma unroll
            for (int q = 0; q < 24; ++q)
                a = fmaf(F[r * 24 + q], Ue[q], a);   // SGPR filter operand
            o[r] = a;
        }

        union { __half2 h[16]; float4 f[4]; } ob;
        #pragma unroll
        for (int c = 0; c < 8; ++c) {
            ob.h[2*c + 0] = __floats2half2_rn(o[3*c + 0], o[3*c + 1]);
            ob.h[2*c + 1] = __floats2half2_rn(o[3*c + 2], 0.0f);
        }
        float4* __restrict__ dst = KUe16 + (size_t)e * 4;   // 64 B, line-aligned
        #pragma unroll
        for (int q = 0; q < 4; ++q) dst[q] = ob.f[q];
    }
}

// K5: per node n, sum corner-slot half4 of the 8 incident elements (8 B loads,
// slab-pinned -> mostly the XCD's own KUe region). fp32 accumulate.
__global__ __launch_bounds__(256) void k5_reduce(
    const uint2* __restrict__ KUe16, float* __restrict__ out)
{
    int b = blockIdx.x;
    int slab  = (b & 7) + 8 * (b >> 9);
    int chunk = (b >> 3) & 63;
    int n = slab * SLAB_EL + chunk * 256 + threadIdx.x;

    int k = n & 63, j = (n >> 6) & 63, i = (n >> 12) & 63;

    const int DI[8] = {0,1,0,1,0,1,0,1};
    const int DJ[8] = {0,0,1,1,0,0,1,1};
    const int DK[8] = {0,0,0,0,1,1,1,1};

    float a0 = 0.f, a1 = 0.f, a2 = 0.f;
    #pragma unroll
    for (int c = 0; c < 8; ++c) {
        int ei = (i - DI[c]) & 63;
        int ej = (j - DJ[c]) & 63;
        int ek = (k - DK[c]) & 63;
        uint2 v = KUe16[(size_t)IDX(ei, ej, ek) * 8 + c];
        union { unsigned u; __half2 h; } ux, uy;
        ux.u = v.x; uy.u = v.y;
        a0 += __low2float(ux.h);
        a1 += __high2float(ux.h);
        a2 += __low2float(uy.h);
    }
    out[n*3 + 0] = a0;
    out[n*3 + 1] = a1;
    out[n*3 + 2] = a2;
}

// Fallback (ws too small): round-1 atomic scatter kernel.
__global__ __launch_bounds__(256) void fe_apply_atomic(
    const float* __restrict__ U, const float* __restrict__ rho,
    const float* __restrict__ filters, float* __restrict__ out)
{
    int e = blockIdx.x * blockDim.x + threadIdx.x;
    int k = e & 63, j = (e >> 6) & 63, i = (e >> 12) & 63;
    int i1 = (i + 1) & 63, j1 = (j + 1) & 63, k1 = (k + 1) & 63;
    int nodes[8];
    nodes[0]=IDX(i,j,k);   nodes[1]=IDX(i1,j,k);   nodes[2]=IDX(i,j1,k);   nodes[3]=IDX(i1,j1,k);
    nodes[4]=IDX(i,j,k1);  nodes[5]=IDX(i1,j,k1);  nodes[6]=IDX(i,j1,k1);  nodes[7]=IDX(i1,j1,k1);
    int t = type_of(rho, i, j, k);
    float Ue[24];
    #pragma unroll
    for (int m = 0; m < 8; ++m) {
        int bb = nodes[m] * 3;
        Ue[3*m+0]=U[bb+0]; Ue[3*m+1]=U[bb+1]; Ue[3*m+2]=U[bb+2];
    }
    const float4* Kr = (const float4*)(filters + t * 576);
    #pragma unroll
    for (int r = 0; r < 24; ++r) {
        float a = 0.f;
        #pragma unroll
        for (int q = 0; q < 6; ++q) {
            float4 f = Kr[r*6+q];
            a = fmaf(f.x,Ue[4*q+0],a); a = fmaf(f.y,Ue[4*q+1],a);
            a = fmaf(f.z,Ue[4*q+2],a); a = fmaf(f.w,Ue[4*q+3],a);
        }
        atomicAdd(&out[nodes[r/3]*3 + (r%3)], a);
    }
}

extern "C" void kernel_launch(void* const* d_in, const int* in_sizes, int n_in,
                              void* d_out, int out_size, void* d_ws, size_t ws_size,
                              hipStream_t stream) {
    const float* U       = (const float*)d_in[0];
    const float* rho     = (const float*)d_in[1];
    const float* filters = (const float*)d_in[3];
    float* out = (float*)d_out;

    if (ws_size < WS_NEEDED) {
        hipMemsetAsync(out, 0, (size_t)out_size * sizeof(float), stream);
        fe_apply_atomic<<<dim3(NEL/256), dim3(256), 0, stream>>>(U, rho, filters, out);
        return;
    }

    char* ws = (char*)d_ws;
    float4*        U4     = (float4*)(ws + WS_U4);
    float4*        KUe16  = (float4*)(ws + WS_KUE);
    int*           sorted = (int*)(ws + WS_SORTED);
    unsigned char* types  = (unsigned char*)(ws + WS_TYPES);
    int*           bhist  = (int*)(ws + WS_BHIST);
    int*           slotinfo = (int*)(ws + WS_SLOT);

    k1_hist   <<<dim3(256),  dim3(1024), 0, stream>>>(U, rho, U4, types, bhist);
    k2_scan   <<<dim3(16),   dim3(256),  0, stream>>>(bhist, slotinfo);
    k3_scatter<<<dim3(256),  dim3(1024), 0, stream>>>(types, bhist, sorted);
    k4_apply  <<<dim3(2048), dim3(256),  0, stream>>>(U4, filters, sorted, slotinfo, KUe16);
    k5_reduce <<<dim3(1024), dim3(256),  0, stream>>>((const uint2*)KUe16, out);
}